// Round 1
// baseline (591.659 us; speedup 1.0000x reference)
//
#include <hip/hip_runtime.h>
#include <math.h>

// GCN fused kernel for MI355X (gfx950). B=4096, N=116, F_IN=116, HID=256, OUT=2.
// R5: GEMM1 A-operand moved global->LDS. X is staged once into ssup (bf16,
// coalesced, converted once); both GEMM1 chunks run from LDS; xw kept in 32
// VGPRs of bf16; ssup then restaged with support (pads stay zeroed). W1T
// chunk-1 restage is T14-split (loads issued under GEMM1 c0). LDS unchanged
// (76.7 KB -> 2 blocks/CU), __launch_bounds__(512,4) holds VGPR <= 128.

#define BDIM 512

constexpr int Bsz = 4096;
constexpr int Nn  = 116;
constexpr int Fin = 116;
constexpr int HID = 256;
constexpr int SK  = 136;            // bf16 row stride (272 B -> bank rotation)
constexpr int NF4 = 3364;           // 116*116/4
constexpr int W1T_ELEMS = 256 * SK; // 34816
constexpr int W2T_OFF   = W1T_ELEMS;

typedef __bf16 bf16;
typedef __bf16 bf16x4 __attribute__((ext_vector_type(4)));
typedef __bf16 bf16x8 __attribute__((ext_vector_type(8)));
typedef float  floatx4 __attribute__((ext_vector_type(4)));

// MFMA 16x16x32 bf16 layout: A-frag A[m=lane&15][k=(lane>>4)*8+j];
// B-frag BT[n=lane&15][k=(lane>>4)*8+j]; C/D col=lane&15, row=(lane>>4)*4+reg.

__global__ __launch_bounds__(1024) void prep_weights(
    const float* __restrict__ W1, const float* __restrict__ W2,
    bf16* __restrict__ WT)
{
  int j = blockIdx.x * 1024 + threadIdx.x;
  if (j < W1T_ELEMS) {                       // W1T[h][kk], kk>=116 zeroed
    int h = j / SK, kk = j - h * SK;
    WT[j] = (bf16)((kk < Fin) ? W1[kk * HID + h] : 0.f);
  } else if (j < W1T_ELEMS + 4 * 264) {      // W2T[n][k], k>=256 zeroed
    int t = j - W1T_ELEMS;
    int n = t / 264, k = t - n * 264;
    WT[j] = (bf16)((k < HID) ? W2[k * 4 + n] : 0.f);
  }
}

// stage a [116][116] fp32 matrix into LDS as bf16 [128][SK]; PADS also zeroes
// cols 116..135 (all 128 rows) and rows 116..127 (cols 0..115).
template <bool PADS>
__device__ __attribute__((always_inline)) inline void stage_mat(
    const float* __restrict__ g, bf16* dst, int tid)
{
  for (int i = tid; i < NF4; i += BDIM) {
    int m  = i / 29;
    int kq = (i - m * 29) * 4;
    float4 u = ((const float4*)g)[i];
    bf16x4 q; q[0]=(bf16)u.x; q[1]=(bf16)u.y; q[2]=(bf16)u.z; q[3]=(bf16)u.w;
    *(bf16x4*)&dst[m * SK + kq] = q;
  }
  if (PADS) {
    bf16x4 z; z[0]=z[1]=z[2]=z[3]=(bf16)0.f;
    for (int i = tid; i < 128 * 5; i += BDIM) {
      int m = i / 5, cc = 116 + (i - m * 5) * 4;
      *(bf16x4*)&dst[m * SK + cc] = z;
    }
    for (int i = tid; i < 12 * 29; i += BDIM) {
      int r = 116 + i / 29, cc = (i - (i / 29) * 29) * 4;
      *(bf16x4*)&dst[r * SK + cc] = z;
    }
  }
}

// one 128x128x128 GEMM quarter: acc += A[128][128] * Bt[128][128]^T, both in
// LDS as bf16 [row][SK].
__device__ __attribute__((always_inline)) inline void gemm128(
    const bf16* A, const bf16* Bt, floatx4 (&acc)[2][4],
    int wm, int wn, int quad, int l16)
{
#pragma unroll
  for (int ks = 0; ks < 4; ++ks) {
    const int k0 = ks * 32 + quad * 8;
    bf16x8 af[2], bfr[4];
#pragma unroll
    for (int mt = 0; mt < 2; ++mt)
      af[mt] = *(const bf16x8*)&A[(wm + mt * 16 + l16) * SK + k0];
#pragma unroll
    for (int nt = 0; nt < 4; ++nt)
      bfr[nt] = *(const bf16x8*)&Bt[(wn + nt * 16 + l16) * SK + k0];
#pragma unroll
    for (int mt = 0; mt < 2; ++mt)
#pragma unroll
      for (int nt = 0; nt < 4; ++nt)
        acc[mt][nt] = __builtin_amdgcn_mfma_f32_16x16x32_bf16(af[mt], bfr[nt], acc[mt][nt], 0, 0, 0);
  }
}

__device__ __attribute__((always_inline)) inline void zero_acc(floatx4 (&acc)[2][4])
{
#pragma unroll
  for (int mt = 0; mt < 2; ++mt)
#pragma unroll
    for (int nt = 0; nt < 4; ++nt) { acc[mt][nt][0]=acc[mt][nt][1]=acc[mt][nt][2]=acc[mt][nt][3]=0.f; }
}

__global__ __launch_bounds__(BDIM, 4) void gcn_fused(
    const float* __restrict__ X, const float* __restrict__ SUPP,
    const bf16* __restrict__ WT,
    const float* __restrict__ B1v, const float* __restrict__ B2v,
    const float* __restrict__ Wr1, const float* __restrict__ br1,
    const float* __restrict__ Wr2, const float* __restrict__ br2,
    float* __restrict__ OUTP)
{
  // 76,736 B LDS -> 2 blocks/CU (16 waves/CU)
  __shared__ __align__(16) bf16 ssup[128 * SK];  // X, then support   34816 B
  __shared__ __align__(16) bf16 swb [128 * SK];  // W1Tc/xwT/h1c      34816 B
  __shared__ __align__(16) bf16 sw2t[4 * 264];   // W2T                2112 B
  __shared__ __align__(16) bf16 stt [4 * SK];    // t^T                1088 B
  __shared__ float sh2[464];                     //                    1856 B
  __shared__ float spart[8 * 64];                //                    2048 B

  const int b    = blockIdx.x;
  const int tid  = threadIdx.x;
  const int wid  = tid >> 6;
  const int lane = tid & 63;
  const int quad = lane >> 4;
  const int l16  = lane & 15;

  // wave grid: 4 m-groups x 2 n-groups; wave tile 32(m) x 64(n)
  const int wm = (wid & 3) * 32;
  const int wn = (wid >> 2) * 64;

  // ---- stage X (fp32 -> bf16) + W1T chunk 0 + W2T ----
  stage_mat<true>(X + (size_t)b * (Nn * Fin), ssup, tid);
  for (int i = tid; i < 2176; i += BDIM)
    ((float4*)swb)[i] = ((const float4*)WT)[i];
  if (tid < 132) ((float4*)sw2t)[tid] = ((const float4*)(WT + W2T_OFF))[tid];
  __syncthreads();  // S0

  // T14: issue W1T chunk-1 loads now; they drain under GEMM1 c0.
  float4 w1pf[5];
#pragma unroll
  for (int j = 0; j < 5; ++j) {
    int i = tid + j * BDIM;
    if (i < 2176) w1pf[j] = ((const float4*)(WT + 128 * SK))[i];
  }

  floatx4 acc[2][4];
  bf16x4  xwb0[2][4], xwb1[2][4];

  // GEMM1 c0: xw0 = X @ W1[:,0:128]  (A,B both LDS)
  zero_acc(acc);
  gemm128(ssup, swb, acc, wm, wn, quad, l16);
#pragma unroll
  for (int mt = 0; mt < 2; ++mt)
#pragma unroll
    for (int nt = 0; nt < 4; ++nt) {
      floatx4 a = acc[mt][nt];
      bf16x4 p; p[0]=(bf16)a[0]; p[1]=(bf16)a[1]; p[2]=(bf16)a[2]; p[3]=(bf16)a[3];
      xwb0[mt][nt] = p;
    }
  __syncthreads();  // S1: W1Tc0 reads done
#pragma unroll
  for (int j = 0; j < 5; ++j) {
    int i = tid + j * BDIM;
    if (i < 2176) ((float4*)swb)[i] = w1pf[j];
  }
  __syncthreads();  // S2: W1Tc1 visible

  // GEMM1 c1
  zero_acc(acc);
  gemm128(ssup, swb, acc, wm, wn, quad, l16);
#pragma unroll
  for (int mt = 0; mt < 2; ++mt)
#pragma unroll
    for (int nt = 0; nt < 4; ++nt) {
      floatx4 a = acc[mt][nt];
      bf16x4 p; p[0]=(bf16)a[0]; p[1]=(bf16)a[1]; p[2]=(bf16)a[2]; p[3]=(bf16)a[3];
      xwb1[mt][nt] = p;
    }
  __syncthreads();  // S3: X + W1Tc1 reads done

  // restage ssup with support (pads still zeroed from X stage); write xwT c0.
  // X rows >=116 were staged as zero, so xw rows >=116 are exactly 0 -> no
  // m-guard needed on the xwT write (m is GEMM2's K).
  stage_mat<false>(SUPP + (size_t)b * (Nn * Nn), ssup, tid);
#pragma unroll
  for (int mt = 0; mt < 2; ++mt)
#pragma unroll
    for (int nt = 0; nt < 4; ++nt) {
      int mb = wm + mt * 16 + quad * 4;
      int n  = wn + nt * 16 + l16;
      *(bf16x4*)&swb[n * SK + mb] = xwb0[mt][nt];
    }
  __syncthreads();  // S4: support + xwT0 visible

  floatx4 acc3; acc3[0]=acc3[1]=acc3[2]=acc3[3]=0.f;  // GEMM3 acc (16 rows/wave)

#pragma unroll
  for (int c = 0; c < 2; ++c) {
    // GEMM2: h1_c = relu(sup @ xw_c + b1_c)
    zero_acc(acc);
    gemm128(ssup, swb, acc, wm, wn, quad, l16);
    __syncthreads();  // xwT_c reads done (swb about to be overwritten)

    // write h1_c into swb as A-layout [m][k_local] (+bias, relu)
#pragma unroll
    for (int mt = 0; mt < 2; ++mt)
#pragma unroll
      for (int nt = 0; nt < 4; ++nt) {
        int mb   = wm + mt * 16 + quad * 4;
        int coll = wn + nt * 16 + l16;
        float bb = B1v[c * 128 + coll];
        floatx4 a = acc[mt][nt];
#pragma unroll
        for (int r = 0; r < 4; ++r)
          swb[(mb + r) * SK + coll] = (bf16)fmaxf(a[r] + bb, 0.f);
      }
    __syncthreads();  // h1c visible

    // GEMM3 partial: t += h1c @ W2[c*128 : c*128+128, :]
#pragma unroll
    for (int ks = 0; ks < 4; ++ks) {
      const int k0 = ks * 32 + quad * 8;
      bf16x8 bfr = *(const bf16x8*)&sw2t[(l16 & 3) * 264 + c * 128 + k0];
      bf16x8 af  = *(const bf16x8*)&swb[(wid * 16 + l16) * SK + k0];
      acc3 = __builtin_amdgcn_mfma_f32_16x16x32_bf16(af, bfr, acc3, 0, 0, 0);
    }
    if (c == 0) {
      __syncthreads();  // h1c0 reads done before xwT c1 overwrite
#pragma unroll
      for (int mt = 0; mt < 2; ++mt)
#pragma unroll
        for (int nt = 0; nt < 4; ++nt) {
          int mb = wm + mt * 16 + quad * 4;
          int n  = wn + nt * 16 + l16;
          *(bf16x4*)&swb[n * SK + mb] = xwb1[mt][nt];
        }
      __syncthreads();  // xwT1 visible
    }
  }

  // write t^T (zero pad m>=116: m is GEMM4's K)
  {
    int mb = wid * 16 + quad * 4;
    bf16x4 p;
    if (mb < Nn) { p[0]=(bf16)acc3[0]; p[1]=(bf16)acc3[1]; p[2]=(bf16)acc3[2]; p[3]=(bf16)acc3[3]; }
    else         { p[0]=p[1]=p[2]=p[3]=(bf16)0.f; }
    if (l16 < 4) *(bf16x4*)&stt[l16 * SK + mb] = p;
  }
  __syncthreads();  // t^T visible

  // GEMM4: h2 = relu(sup @ t + b2)  (16 rows/wave)
  floatx4 acc4; acc4[0]=acc4[1]=acc4[2]=acc4[3]=0.f;
#pragma unroll
  for (int ks = 0; ks < 4; ++ks) {
    const int k0 = ks * 32 + quad * 8;
    bf16x8 af  = *(const bf16x8*)&ssup[(wid * 16 + l16) * SK + k0];
    bf16x8 bfr = *(const bf16x8*)&stt[(l16 & 3) * SK + k0];
    acc4 = __builtin_amdgcn_mfma_f32_16x16x32_bf16(af, bfr, acc4, 0, 0, 0);
  }
  if (l16 < 4) {
    float bb = B2v[l16];
#pragma unroll
    for (int r = 0; r < 4; ++r) {
      int m = wid * 16 + quad * 4 + r;
      if (m < Nn) sh2[m * 4 + l16] = fmaxf(acc4[r] + bb, 0.f);
    }
  }
  __syncthreads();  // sh2 visible

  // readout: r = relu(flat @ Wr1 + br1); out = log_softmax(r @ Wr2 + br2)
  {
    int j   = tid & 63;      // output unit
    int ksl = tid >> 6;      // k-split 0..7 (58 k each)
    int kb  = ksl * 58;
    float p = 0.f;
#pragma unroll 4
    for (int kk = 0; kk < 58; ++kk)
      p = fmaf(sh2[kb + kk], Wr1[(kb + kk) * 64 + j], p);  // coalesced, L2-hot
    spart[ksl * 64 + j] = p;
  }
  __syncthreads();
  if (tid < 64) {
    int j = tid;
    float r = 0.f;
#pragma unroll
    for (int s = 0; s < 8; ++s) r += spart[s * 64 + j];
    r = fmaxf(r + br1[j], 0.f);
    float p0 = r * Wr2[j * 2 + 0];
    float p1 = r * Wr2[j * 2 + 1];
#pragma unroll
    for (int off = 32; off > 0; off >>= 1) {
      p0 += __shfl_xor(p0, off, 64);
      p1 += __shfl_xor(p1, off, 64);
    }
    float l0 = p0 + br2[0], l1 = p1 + br2[1];
    float mx  = fmaxf(l0, l1);
    float lse = mx + logf(expf(l0 - mx) + expf(l1 - mx));
    if (j < 2) OUTP[(size_t)b * 2 + j] = (j ? l1 : l0) - lse;
  }
}

extern "C" void kernel_launch(void* const* d_in, const int* in_sizes, int n_in,
                              void* d_out, int out_size, void* d_ws, size_t ws_size,
                              hipStream_t stream) {
  const float* X    = (const float*)d_in[0];
  const float* SUPP = (const float*)d_in[1];
  const float* W1   = (const float*)d_in[2];
  const float* B1v  = (const float*)d_in[3];
  const float* W2   = (const float*)d_in[4];
  const float* B2v  = (const float*)d_in[5];
  const float* Wr1  = (const float*)d_in[6];
  const float* br1  = (const float*)d_in[7];
  const float* Wr2  = (const float*)d_in[8];
  const float* br2  = (const float*)d_in[9];
  bf16* WT = (bf16*)d_ws;  // 71.7 KB: W1T [256][136] + W2T [4][264]

  prep_weights<<<36, 1024, 0, stream>>>(W1, W2, WT);
  gcn_fused<<<Bsz, BDIM, 0, stream>>>(X, SUPP, WT, B1v, B2v,
                                      Wr1, br1, Wr2, br2, (float*)d_out);
}

// Round 2
// 551.779 us; speedup vs baseline: 1.0723x; 1.0723x over previous
//
#include <hip/hip_runtime.h>
#include <math.h>

// GCN fused kernel for MI355X (gfx950). B=4096, N=116, F_IN=116, HID=256, OUT=2.
// R6: spill fix + phase merge.
//  - X lives in 32 VGPRs/lane (per-wave-private GEMM1 A-fragments, fp32->bf16
//    converted once at start); no X LDS staging, no A-side ds_reads in GEMM1.
//  - ssup holds SUPPORT from kernel start -> both big HBM reads (X frags +
//    SUPP) issue in one burst; SUPP latency hides before GEMM2.
//  - ALL WT staging via __builtin_amdgcn_global_load_lds (width 16): zero
//    VGPR cost, async, drained by the pre-barrier vmcnt(0). No register
//    prefetch arrays held across GEMMs -> no scratch (R5 spilled 139 MB).
//  - LDS 76.7 KB -> 2 blocks/CU; launch_bounds(512,4) caps unified regs at
//    128 (est. peak live ~103).

#define BDIM 512

constexpr int Bsz = 4096;
constexpr int Nn  = 116;
constexpr int Fin = 116;
constexpr int HID = 256;
constexpr int SK  = 136;            // bf16 row stride (272 B -> bank rotation)
constexpr int NF4 = 3364;           // 116*116/4
constexpr int W1T_ELEMS = 256 * SK; // 34816
constexpr int W2T_OFF   = W1T_ELEMS;

typedef __bf16 bf16;
typedef __bf16 bf16x4 __attribute__((ext_vector_type(4)));
typedef __bf16 bf16x8 __attribute__((ext_vector_type(8)));
typedef float  floatx4 __attribute__((ext_vector_type(4)));

// MFMA 16x16x32 bf16 layout: A-frag A[m=lane&15][k=(lane>>4)*8+j];
// B-frag BT[n=lane&15][k=(lane>>4)*8+j]; C/D col=lane&15, row=(lane>>4)*4+reg.

__global__ __launch_bounds__(1024) void prep_weights(
    const float* __restrict__ W1, const float* __restrict__ W2,
    bf16* __restrict__ WT)
{
  int j = blockIdx.x * 1024 + threadIdx.x;
  if (j < W1T_ELEMS) {                       // W1T[h][kk], kk>=116 zeroed
    int h = j / SK, kk = j - h * SK;
    WT[j] = (bf16)((kk < Fin) ? W1[kk * HID + h] : 0.f);
  } else if (j < W1T_ELEMS + 4 * 264) {      // W2T[n][k], k>=256 zeroed
    int t = j - W1T_ELEMS;
    int n = t / 264, k = t - n * 264;
    WT[j] = (bf16)((k < HID) ? W2[k * 4 + n] : 0.f);
  }
}

// async global->LDS, 16 B per lane. LDS dest = wave-uniform base + lane*16
// (HW adds the lane offset); global src is per-lane.
__device__ __forceinline__ void gl2lds16(const void* g, void* l) {
  __builtin_amdgcn_global_load_lds(
      (const __attribute__((address_space(1))) void*)g,
      (__attribute__((address_space(3))) void*)l, 16, 0, 0);
}

// one 128x128x128 GEMM quarter, A from LDS (used by GEMM2)
__device__ __attribute__((always_inline)) inline void gemm128(
    const bf16* A, const bf16* Bt, floatx4 (&acc)[2][4],
    int wm, int wn, int quad, int l16)
{
#pragma unroll
  for (int ks = 0; ks < 4; ++ks) {
    const int k0 = ks * 32 + quad * 8;
    bf16x8 af[2], bfr[4];
#pragma unroll
    for (int mt = 0; mt < 2; ++mt)
      af[mt] = *(const bf16x8*)&A[(wm + mt * 16 + l16) * SK + k0];
#pragma unroll
    for (int nt = 0; nt < 4; ++nt)
      bfr[nt] = *(const bf16x8*)&Bt[(wn + nt * 16 + l16) * SK + k0];
#pragma unroll
    for (int mt = 0; mt < 2; ++mt)
#pragma unroll
      for (int nt = 0; nt < 4; ++nt)
        acc[mt][nt] = __builtin_amdgcn_mfma_f32_16x16x32_bf16(af[mt], bfr[nt], acc[mt][nt], 0, 0, 0);
  }
}

// GEMM1 quarter: A from registers (per-wave-private X fragments)
__device__ __attribute__((always_inline)) inline void gemm128_ra(
    const bf16x8 (&xf)[2][4], const bf16* Bt, floatx4 (&acc)[2][4],
    int wn, int quad, int l16)
{
#pragma unroll
  for (int ks = 0; ks < 4; ++ks) {
    const int k0 = ks * 32 + quad * 8;
    bf16x8 bfr[4];
#pragma unroll
    for (int nt = 0; nt < 4; ++nt)
      bfr[nt] = *(const bf16x8*)&Bt[(wn + nt * 16 + l16) * SK + k0];
#pragma unroll
    for (int mt = 0; mt < 2; ++mt)
#pragma unroll
      for (int nt = 0; nt < 4; ++nt)
        acc[mt][nt] = __builtin_amdgcn_mfma_f32_16x16x32_bf16(xf[mt][ks], bfr[nt], acc[mt][nt], 0, 0, 0);
  }
}

__device__ __attribute__((always_inline)) inline void zero_acc(floatx4 (&acc)[2][4])
{
#pragma unroll
  for (int mt = 0; mt < 2; ++mt)
#pragma unroll
    for (int nt = 0; nt < 4; ++nt) { acc[mt][nt][0]=acc[mt][nt][1]=acc[mt][nt][2]=acc[mt][nt][3]=0.f; }
}

__global__ __launch_bounds__(BDIM, 4) void gcn_fused(
    const float* __restrict__ X, const float* __restrict__ SUPP,
    const bf16* __restrict__ WT,
    const float* __restrict__ B1v, const float* __restrict__ B2v,
    const float* __restrict__ Wr1, const float* __restrict__ br1,
    const float* __restrict__ Wr2, const float* __restrict__ br2,
    float* __restrict__ OUTP)
{
  // 76,736 B LDS -> 2 blocks/CU (16 waves/CU)
  __shared__ __align__(16) bf16 ssup[128 * SK];  // support (whole kernel) 34816 B
  __shared__ __align__(16) bf16 swb [128 * SK];  // W1Tc0/c1, xwT, h1c    34816 B
  __shared__ __align__(16) bf16 sw2t[4 * 264];   // W2T                    2112 B
  __shared__ __align__(16) bf16 stt [4 * SK];    // t^T                    1088 B
  __shared__ float sh2[464];                     //                        1856 B
  __shared__ float spart[8 * 64];                //                        2048 B

  const int b    = blockIdx.x;
  const int tid  = threadIdx.x;
  const int wid  = tid >> 6;
  const int lane = tid & 63;
  const int quad = lane >> 4;
  const int l16  = lane & 15;

  // wave grid: 4 m-groups x 2 n-groups; wave tile 32(m) x 64(n)
  const int wm = (wid & 3) * 32;
  const int wn = (wid >> 2) * 64;

  // ---- burst: everything issues here (max HBM concurrency) ----
  // W1T chunk 0 -> swb, W2T -> sw2t via global_load_lds (no VGPRs)
  {
    const char* wg = (const char*)WT;
    char* wl = (char*)swb;
    for (int off = wid * 1024; off < 34816; off += 8 * 1024)
      gl2lds16(wg + off + lane * 16, wl + off);
    if (wid == 7) {                 // 2112 B of W2T on a 4-chunk wave
      const char* w2g = (const char*)(WT + W2T_OFF);
      char* w2l = (char*)sw2t;
      gl2lds16(w2g + lane * 16, w2l);
      gl2lds16(w2g + 1024 + lane * 16, w2l + 1024);
      if (lane < 4) gl2lds16(w2g + 2048 + lane * 16, w2l + 2048);
    }
  }

  // X fragments -> registers (rows wm..wm+31 only; same frags feed both
  // GEMM1 chunks). Rows >=116 zeroed so xw rows >=116 are exactly 0.
  const float* xrow = X + (size_t)b * (Nn * Fin);
  bf16x8 xf[2][4];
#pragma unroll
  for (int mt = 0; mt < 2; ++mt) {
    const int row = wm + mt * 16 + l16;
    const bool rv = row < Nn;
    const float* pr = xrow + (rv ? row : 0) * Fin;
#pragma unroll
    for (int ks = 0; ks < 4; ++ks) {
      const int k0 = ks * 32 + quad * 8;
      float4 u0 = make_float4(0.f, 0.f, 0.f, 0.f);
      float4 u1 = make_float4(0.f, 0.f, 0.f, 0.f);
      if (ks < 3 || quad < 3) u0 = *(const float4*)(pr + k0);       // k0+3 <= 115
      if (ks < 3 || quad < 2) u1 = *(const float4*)(pr + k0 + 4);   // k0+7 <= 115
      bf16x8 f;
      f[0]=(bf16)u0.x; f[1]=(bf16)u0.y; f[2]=(bf16)u0.z; f[3]=(bf16)u0.w;
      f[4]=(bf16)u1.x; f[5]=(bf16)u1.y; f[6]=(bf16)u1.z; f[7]=(bf16)u1.w;
      bf16x8 z; 
#pragma unroll
      for (int j = 0; j < 8; ++j) z[j] = (bf16)0.f;
      xf[mt][ks] = rv ? f : z;
    }
  }

  // SUPPORT stage (fp32 -> bf16) into ssup, + zero pads
  {
    const float4* sg = (const float4*)(SUPP + (size_t)b * (Nn * Nn));
    for (int i = tid; i < NF4; i += BDIM) {
      int m  = i / 29;
      int kq = (i - m * 29) * 4;
      float4 u = sg[i];
      bf16x4 q; q[0]=(bf16)u.x; q[1]=(bf16)u.y; q[2]=(bf16)u.z; q[3]=(bf16)u.w;
      *(bf16x4*)&ssup[m * SK + kq] = q;
    }
    bf16x4 z; z[0]=z[1]=z[2]=z[3]=(bf16)0.f;
    for (int i = tid; i < 128 * 5; i += BDIM) {      // K-pad cols 116..135
      int m = i / 5, cc = 116 + (i - m * 5) * 4;
      *(bf16x4*)&ssup[m * SK + cc] = z;
    }
    for (int i = tid; i < 12 * 29; i += BDIM) {      // rows 116..127 (NaN insurance)
      int r = 116 + i / 29, cc = (i - (i / 29) * 29) * 4;
      *(bf16x4*)&ssup[r * SK + cc] = z;
    }
  }
  asm volatile("s_waitcnt vmcnt(0)" ::: "memory");
  __syncthreads();  // S0: W1Tc0+W2T (gl_lds) + support + X regs all ready

  floatx4 acc[2][4];
  bf16x4  xwb0[2][4], xwb1[2][4];

  // GEMM1 c0: xw0 = X @ W1[:,0:128]  (A regs, B LDS)
  zero_acc(acc);
  gemm128_ra(xf, swb, acc, wn, quad, l16);
#pragma unroll
  for (int mt = 0; mt < 2; ++mt)
#pragma unroll
    for (int nt = 0; nt < 4; ++nt) {
      floatx4 a = acc[mt][nt];
      bf16x4 p; p[0]=(bf16)a[0]; p[1]=(bf16)a[1]; p[2]=(bf16)a[2]; p[3]=(bf16)a[3];
      xwb0[mt][nt] = p;
    }
  __syncthreads();  // S1: W1Tc0 reads done

  // restage W1T chunk 1 via global_load_lds (L2-hot, no VGPRs)
  {
    const char* wg = (const char*)(WT + 128 * SK);
    char* wl = (char*)swb;
    for (int off = wid * 1024; off < 34816; off += 8 * 1024)
      gl2lds16(wg + off + lane * 16, wl + off);
  }
  asm volatile("s_waitcnt vmcnt(0)" ::: "memory");
  __syncthreads();  // S2: W1Tc1 visible

  // GEMM1 c1
  zero_acc(acc);
  gemm128_ra(xf, swb, acc, wn, quad, l16);
#pragma unroll
  for (int mt = 0; mt < 2; ++mt)
#pragma unroll
    for (int nt = 0; nt < 4; ++nt) {
      floatx4 a = acc[mt][nt];
      bf16x4 p; p[0]=(bf16)a[0]; p[1]=(bf16)a[1]; p[2]=(bf16)a[2]; p[3]=(bf16)a[3];
      xwb1[mt][nt] = p;
    }
  __syncthreads();  // S3: W1Tc1 reads done

  // write xw^T c0 into swb (xw rows >=116 are 0 by construction -> no guard)
#pragma unroll
  for (int mt = 0; mt < 2; ++mt)
#pragma unroll
    for (int nt = 0; nt < 4; ++nt) {
      int mb = wm + mt * 16 + quad * 4;
      int n  = wn + nt * 16 + l16;
      *(bf16x4*)&swb[n * SK + mb] = xwb0[mt][nt];
    }
  __syncthreads();  // S4: xwT0 visible (support staged since S0)

  floatx4 acc3; acc3[0]=acc3[1]=acc3[2]=acc3[3]=0.f;  // GEMM3 acc (16 rows/wave)

#pragma unroll
  for (int c = 0; c < 2; ++c) {
    // GEMM2: h1_c = relu(sup @ xw_c + b1_c)
    zero_acc(acc);
    gemm128(ssup, swb, acc, wm, wn, quad, l16);
    __syncthreads();  // xwT_c reads done (swb about to be overwritten)

    // write h1_c into swb as A-layout [m][k_local] (+bias, relu)
#pragma unroll
    for (int mt = 0; mt < 2; ++mt)
#pragma unroll
      for (int nt = 0; nt < 4; ++nt) {
        int mb   = wm + mt * 16 + quad * 4;
        int coll = wn + nt * 16 + l16;
        float bb = B1v[c * 128 + coll];
        floatx4 a = acc[mt][nt];
#pragma unroll
        for (int r = 0; r < 4; ++r)
          swb[(mb + r) * SK + coll] = (bf16)fmaxf(a[r] + bb, 0.f);
      }
    __syncthreads();  // h1c visible

    // GEMM3 partial: t += h1c @ W2[c*128 : c*128+128, :]
#pragma unroll
    for (int ks = 0; ks < 4; ++ks) {
      const int k0 = ks * 32 + quad * 8;
      bf16x8 bfr = *(const bf16x8*)&sw2t[(l16 & 3) * 264 + c * 128 + k0];
      bf16x8 af  = *(const bf16x8*)&swb[(wid * 16 + l16) * SK + k0];
      acc3 = __builtin_amdgcn_mfma_f32_16x16x32_bf16(af, bfr, acc3, 0, 0, 0);
    }
    if (c == 0) {
      __syncthreads();  // h1c0 reads done before xwT c1 overwrite
#pragma unroll
      for (int mt = 0; mt < 2; ++mt)
#pragma unroll
        for (int nt = 0; nt < 4; ++nt) {
          int mb = wm + mt * 16 + quad * 4;
          int n  = wn + nt * 16 + l16;
          *(bf16x4*)&swb[n * SK + mb] = xwb1[mt][nt];
        }
      __syncthreads();  // xwT1 visible
    }
  }

  // write t^T (zero pad m>=116: m is GEMM4's K)
  {
    int mb = wid * 16 + quad * 4;
    bf16x4 p;
    if (mb < Nn) { p[0]=(bf16)acc3[0]; p[1]=(bf16)acc3[1]; p[2]=(bf16)acc3[2]; p[3]=(bf16)acc3[3]; }
    else         { p[0]=p[1]=p[2]=p[3]=(bf16)0.f; }
    if (l16 < 4) *(bf16x4*)&stt[l16 * SK + mb] = p;
  }
  __syncthreads();  // t^T visible

  // GEMM4: h2 = relu(sup @ t + b2)  (16 rows/wave)
  floatx4 acc4; acc4[0]=acc4[1]=acc4[2]=acc4[3]=0.f;
#pragma unroll
  for (int ks = 0; ks < 4; ++ks) {
    const int k0 = ks * 32 + quad * 8;
    bf16x8 af  = *(const bf16x8*)&ssup[(wid * 16 + l16) * SK + k0];
    bf16x8 bfr = *(const bf16x8*)&stt[(l16 & 3) * SK + k0];
    acc4 = __builtin_amdgcn_mfma_f32_16x16x32_bf16(af, bfr, acc4, 0, 0, 0);
  }
  if (l16 < 4) {
    float bb = B2v[l16];
#pragma unroll
    for (int r = 0; r < 4; ++r) {
      int m = wid * 16 + quad * 4 + r;
      if (m < Nn) sh2[m * 4 + l16] = fmaxf(acc4[r] + bb, 0.f);
    }
  }
  __syncthreads();  // sh2 visible

  // readout: r = relu(flat @ Wr1 + br1); out = log_softmax(r @ Wr2 + br2)
  {
    int j   = tid & 63;      // output unit
    int ksl = tid >> 6;      // k-split 0..7 (58 k each)
    int kb  = ksl * 58;
    float p = 0.f;
#pragma unroll 4
    for (int kk = 0; kk < 58; ++kk)
      p = fmaf(sh2[kb + kk], Wr1[(kb + kk) * 64 + j], p);  // coalesced, L2-hot
    spart[ksl * 64 + j] = p;
  }
  __syncthreads();
  if (tid < 64) {
    int j = tid;
    float r = 0.f;
#pragma unroll
    for (int s = 0; s < 8; ++s) r += spart[s * 64 + j];
    r = fmaxf(r + br1[j], 0.f);
    float p0 = r * Wr2[j * 2 + 0];
    float p1 = r * Wr2[j * 2 + 1];
#pragma unroll
    for (int off = 32; off > 0; off >>= 1) {
      p0 += __shfl_xor(p0, off, 64);
      p1 += __shfl_xor(p1, off, 64);
    }
    float l0 = p0 + br2[0], l1 = p1 + br2[1];
    float mx  = fmaxf(l0, l1);
    float lse = mx + logf(expf(l0 - mx) + expf(l1 - mx));
    if (j < 2) OUTP[(size_t)b * 2 + j] = (j ? l1 : l0) - lse;
  }
}

extern "C" void kernel_launch(void* const* d_in, const int* in_sizes, int n_in,
                              void* d_out, int out_size, void* d_ws, size_t ws_size,
                              hipStream_t stream) {
  const float* X    = (const float*)d_in[0];
  const float* SUPP = (const float*)d_in[1];
  const float* W1   = (const float*)d_in[2];
  const float* B1v  = (const float*)d_in[3];
  const float* W2   = (const float*)d_in[4];
  const float* B2v  = (const float*)d_in[5];
  const float* Wr1  = (const float*)d_in[6];
  const float* br1  = (const float*)d_in[7];
  const float* Wr2  = (const float*)d_in[8];
  const float* br2  = (const float*)d_in[9];
  bf16* WT = (bf16*)d_ws;  // 71.7 KB: W1T [256][136] + W2T [4][264]

  prep_weights<<<36, 1024, 0, stream>>>(W1, W2, WT);
  gcn_fused<<<Bsz, BDIM, 0, stream>>>(X, SUPP, WT, B1v, B2v,
                                      Wr1, br1, Wr2, br2, (float*)d_out);
}